// Round 7
// baseline (121.735 us; speedup 1.0000x reference)
//
#include <hip/hip_runtime.h>
#include <math.h>

// HW exp2 (v_exp_f32) when available.
#if defined(__has_builtin)
#  if __has_builtin(__builtin_amdgcn_exp2f)
#    define EXP2F(x) __builtin_amdgcn_exp2f(x)
#  endif
#endif
#ifndef EXP2F
#  define EXP2F(x) __expf(0.69314718055994530942f * (x))
#endif

#if defined(__has_builtin)
#  if __has_builtin(__builtin_amdgcn_fmed3f)
#    define MED3F(a, b, c) __builtin_amdgcn_fmed3f((a), (b), (c))
#  endif
#endif
#ifndef MED3F
#  define MED3F(a, b, c) fminf(fmaxf((a), (b)), (c))
#endif

// R10: R9 pinned the pipe model — v_exp_f32 ~8 cyc/wave64 but trans and
// VALU serialize on the SIMD port (all-trans won vs hybrid by only 5.7us).
// Per-z floor = 8 trans + 6 VALU cyc; kernel-sum ~35 us vs ~23 floor.
// Boundary cost ~4.5us each (R4 vs R6 fixed-cost delta). This round:
// (1) merge tiny L2+L3 into one kernel (block-per-row, h3 stays in LDS,
//     one boundary + one launch gone; L0/L1 keep full 1024-block width),
// (2) polish: explicit v_med3 clamp, unroll-4 ic loop.
// Gate: >=116us refutes the boundary lever -> declare structural roofline.

// ---------------- L0/L1 kernel (validated R9 structure) ----------------
template <int IN, int OUT, int BB, bool FIRST>
__launch_bounds__(256, 4)
__global__ void or_layer(const float* __restrict__ hin,
                         const float* __restrict__ W,
                         const float* __restrict__ tau_ptr,
                         float* __restrict__ hout,
                         float tau_floor) {
  constexpr int OBB = 2;                 // outputs per 16-lane group
  constexpr int NIT = IN / 64;           // 16 lanes x float4 per iter
  constexpr int nOT = OUT / 32;          // 4 waves x 8 outputs per block
  constexpr int IN4 = IN / 4;            // row length in float4

  __shared__ float4 lds_h[BB * IN4];

  const int tid  = threadIdx.x;
  const int lane = tid & 63;
  const int wid  = tid >> 6;
  const int il   = lane & 15;            // i-lane within group
  const int og   = lane >> 4;            // o-group 0..3

  const int ot = blockIdx.x % nOT;
  const int bt = blockIdx.x / nOT;
  const int b0 = bt * BB;
  const int o0 = ot * 32 + wid * 8 + og * OBB;

  const float ta  = tau_ptr[0];
  const float tau = tau_floor + (ta >= 0.0f ? ta : 0.05f * ta);
  const float c2  = tau * 1.44269504088896340736f;  // tau * log2(e)
  const float c01 = 0.1f * c2;           // folded leaky slope
  const float c09 = 0.9f * c2;

  const float4* __restrict__ Wv = (const float4*)W;
  const float4* __restrict__ Hv = (const float4*)hin;

  if (FIRST) {
    // hin is x: (128, IN/2); h = concat(x, 1-x).
    constexpr int HALF4 = IN / 8;
    for (int idx = tid; idx < BB * HALF4; idx += 256) {
      const int r = idx / HALF4;
      const int k = idx - r * HALF4;
      const float4 v = Hv[(b0 + r) * HALF4 + k];
      lds_h[r * IN4 + k] = v;
      lds_h[r * IN4 + HALF4 + k] =
          make_float4(1.0f - v.x, 1.0f - v.y, 1.0f - v.z, 1.0f - v.w);
    }
  } else {
    for (int idx = tid; idx < BB * IN4; idx += 256) {
      const int r = idx / IN4;
      const int k = idx - r * IN4;
      lds_h[r * IN4 + k] = Hv[(b0 + r) * IN4 + k];
    }
  }
  __syncthreads();

  float s[BB][OBB], t[BB][OBB];
#pragma unroll
  for (int r = 0; r < BB; ++r)
#pragma unroll
    for (int c = 0; c < OBB; ++c) { s[r][c] = 0.0f; t[r][c] = 0.0f; }

  // W stream: software pipeline, prefetch distance = 1 ic iteration.
  const float4* wp0 = Wv + (size_t)(o0 + 0) * IN4 + il;
  const float4* wp1 = Wv + (size_t)(o0 + 1) * IN4 + il;
  float4 wcur0 = wp0[0];
  float4 wcur1 = wp1[0];

#pragma unroll 4
  for (int ic = 0; ic < NIT; ++ic) {
    const int icn = (ic + 1 < NIT) ? (ic + 1) : (NIT - 1);
    const float4 wnxt0 = wp0[icn * 16];
    const float4 wnxt1 = wp1[icn * 16];

    float hc[BB][4];
#pragma unroll
    for (int r = 0; r < BB; ++r) {
      const float4 v = lds_h[r * IN4 + ic * 16 + il];
      hc[r][0] = v.x; hc[r][1] = v.y; hc[r][2] = v.z; hc[r][3] = v.w;
    }

    // cw = c2 * leaky_clamp(w): v_med3 clamp + folded-constant fma,
    // built once per ic, reused across BB rows.
    float cw[OBB][4];
    {
      const float wj0[4] = {wcur0.x, wcur0.y, wcur0.z, wcur0.w};
      const float wj1[4] = {wcur1.x, wcur1.y, wcur1.z, wcur1.w};
#pragma unroll
      for (int j = 0; j < 4; ++j) {
        float m  = MED3F(wj0[j], 0.0f, 1.0f);
        cw[0][j] = fmaf(wj0[j], c01, m * c09);
        m        = MED3F(wj1[j], 0.0f, 1.0f);
        cw[1][j] = fmaf(wj1[j], c01, m * c09);
      }
    }

    // All-trans inner loop: per z = 1 mul + v_exp (trans) + 1 add + 1 fma.
#pragma unroll
    for (int r = 0; r < BB; ++r)
#pragma unroll
      for (int c = 0; c < OBB; ++c)
#pragma unroll
        for (int j = 0; j < 4; ++j) {
          const float arg = cw[c][j] * hc[r][j];
          const float e = EXP2F(arg);
          s[r][c] += e;
          t[r][c]  = fmaf(arg, e, t[r][c]);
        }

    wcur0 = wnxt0;
    wcur1 = wnxt1;
  }

  // Reduce partials across the 16 i-lanes of each group.
#pragma unroll
  for (int m = 1; m < 16; m <<= 1)
#pragma unroll
    for (int r = 0; r < BB; ++r)
#pragma unroll
      for (int c = 0; c < OBB; ++c) {
        s[r][c] += __shfl_xor(s[r][c], m, 64);
        t[r][c] += __shfl_xor(t[r][c], m, 64);
      }

  if (il == 0) {
    const float inv_c2 = 1.0f / c2;
#pragma unroll
    for (int r = 0; r < BB; ++r)
#pragma unroll
      for (int c = 0; c < OBB; ++c) {
        const float out = t[r][c] / s[r][c] * inv_c2;  // sum(z e)/sum(e)
        hout[(b0 + r) * OUT + (o0 + c)] = 1.0f - out;
      }
  }
}

// ---------------- L2+L3 fused tail: one block per batch row ----------------
// 512 threads = 32 groups of 16 lanes. h3 row never leaves LDS.
template <int IN, int OUT, bool LAST>
__device__ __forceinline__ void tail_sub(const float4* __restrict__ in4,
                                         const float* __restrict__ W,
                                         const float* __restrict__ tau_ptr,
                                         float tau_floor,
                                         float* __restrict__ out_lds,
                                         float* __restrict__ out_glob) {
  constexpr int NIT = IN / 64;
  constexpr int IN4 = IN / 4;
  constexpr int OPG = OUT / 32;          // outputs per 16-lane group

  const int tid = threadIdx.x;
  const int il  = tid & 15;
  const int g   = tid >> 4;              // 0..31, wave-aligned groups

  const float ta  = tau_ptr[0];
  const float tau = tau_floor + (ta >= 0.0f ? ta : 0.05f * ta);
  const float c2  = tau * 1.44269504088896340736f;
  const float c01 = 0.1f * c2;
  const float c09 = 0.9f * c2;
  const float inv_c2 = 1.0f / c2;

  const float4* __restrict__ Wv = (const float4*)W;

#pragma unroll
  for (int ob = 0; ob < OPG / 2; ++ob) {
    const int o0 = g * OPG + ob * 2;
    float s0 = 0.0f, s1 = 0.0f, t0 = 0.0f, t1 = 0.0f;

#pragma unroll
    for (int ic = 0; ic < NIT; ++ic) {
      const float4 hv = in4[ic * 16 + il];
      const float4 w0 = Wv[(size_t)(o0 + 0) * IN4 + ic * 16 + il];
      const float4 w1 = Wv[(size_t)(o0 + 1) * IN4 + ic * 16 + il];
      const float h[4] = {hv.x, hv.y, hv.z, hv.w};
      const float a[4] = {w0.x, w0.y, w0.z, w0.w};
      const float b[4] = {w1.x, w1.y, w1.z, w1.w};
#pragma unroll
      for (int j = 0; j < 4; ++j) {
        float m = MED3F(a[j], 0.0f, 1.0f);
        const float ca = fmaf(a[j], c01, m * c09);
        m = MED3F(b[j], 0.0f, 1.0f);
        const float cb = fmaf(b[j], c01, m * c09);
        const float arga = ca * h[j];
        const float argb = cb * h[j];
        const float ea = EXP2F(arga);
        const float eb = EXP2F(argb);
        s0 += ea; t0 = fmaf(arga, ea, t0);
        s1 += eb; t1 = fmaf(argb, eb, t1);
      }
    }

#pragma unroll
    for (int m = 1; m < 16; m <<= 1) {
      s0 += __shfl_xor(s0, m, 64); t0 += __shfl_xor(t0, m, 64);
      s1 += __shfl_xor(s1, m, 64); t1 += __shfl_xor(t1, m, 64);
    }

    if (il == 0) {
      const float r0 = 1.0f - t0 / s0 * inv_c2;          // invert
      const float r1 = 1.0f - t1 / s1 * inv_c2;
      if (LAST) { out_glob[o0] = r0; out_glob[o0 + 1] = r1; }
      else      { out_lds[o0]  = r0; out_lds[o0 + 1]  = r1; }
    }
  }
}

__launch_bounds__(512)
__global__ void fused_tail23(const float* __restrict__ h2,
                             const float* __restrict__ W2, const float* __restrict__ tau2,
                             const float* __restrict__ W3, const float* __restrict__ tau3,
                             float* __restrict__ out,
                             float tf_b, float tf_c) {
  __shared__ float4 hB[128];             // 512 floats (h2 row)
  __shared__ float4 hC[64];              // 256 floats (h3 row, never global)

  const int row = blockIdx.x;
  const int tid = threadIdx.x;

  if (tid < 128) hB[tid] = ((const float4*)h2)[row * 128 + tid];
  __syncthreads();

  tail_sub<512, 256, false>(hB, W2, tau2, tf_b, (float*)hC, nullptr);
  __syncthreads();
  tail_sub<256, 128, true >(hC, W3, tau3, tf_c, nullptr, out + row * 128);
}

extern "C" void kernel_launch(void* const* d_in, const int* in_sizes, int n_in,
                              void* d_out, int out_size, void* d_ws, size_t ws_size,
                              hipStream_t stream) {
  // setup_inputs() dict order: x, W0, tau0, W1, tau1, W2, tau2, W3, tau3
  const float* x    = (const float*)d_in[0];
  const float* W0   = (const float*)d_in[1];
  const float* tau0 = (const float*)d_in[2];
  const float* W1   = (const float*)d_in[3];
  const float* tau1 = (const float*)d_in[4];
  const float* W2   = (const float*)d_in[5];
  const float* tau2 = (const float*)d_in[6];
  const float* W3   = (const float*)d_in[7];
  const float* tau3 = (const float*)d_in[8];

  float* h1  = (float*)d_ws;        // 128*1024 floats
  float* h2  = h1 + 128 * 1024;     // 128*512
  float* out = (float*)d_out;       // 128*128

  const double LOGR = 2.9444389791664403;  // log(0.95) - log(0.05) = log(19)
  const float tf1024 = (float)(log(1023.0) + LOGR);
  const float tf512  = (float)(log(511.0)  + LOGR);
  const float tf256  = (float)(log(255.0)  + LOGR);

  // L0, L1 at full machine width (validated config); L2+L3 fused.
  or_layer<1024, 1024, 4, true ><<<1024, 256, 0, stream>>>(x,  W0, tau0, h1, tf1024);
  or_layer<1024,  512, 2, false><<<1024, 256, 0, stream>>>(h1, W1, tau1, h2, tf1024);
  fused_tail23<<<128, 512, 0, stream>>>(h2, W2, tau2, W3, tau3, out, tf512, tf256);
}

// Round 8
// 117.455 us; speedup vs baseline: 1.0364x; 1.0364x over previous
//
#include <hip/hip_runtime.h>
#include <math.h>

// HW exp2 (v_exp_f32) when available.
#if defined(__has_builtin)
#  if __has_builtin(__builtin_amdgcn_exp2f)
#    define EXP2F(x) __builtin_amdgcn_exp2f(x)
#  endif
#endif
#ifndef EXP2F
#  define EXP2F(x) __expf(0.69314718055994530942f * (x))
#endif

// R11 (terminal): pure revert to the best-measured R9 configuration
// (118.1 us). R10's bundle (L2+L3 merge + unroll-4 + med3) regressed to
// 121.7, firing the pre-committed gate: the boundary lever is refuted.
// Lever ledger across the session:
//   confirmed:  all-trans exp on the 8-cyc/wave64 trans pipe (R9, -5.7us)
//   refuted:    occupancy (R3), LDS/prefetch memory path (R4), coop
//               grid.sync fusion (R5, ~170us/sync), block-per-row fusion
//               (R6), producer-consumer flags (R7, acquire-storm), packed
//               FP32 (R8, no dual-issue headroom on gfx950), boundary
//               merge (R10).
// Accounting: ~40us harness fill + ~20-25us serialized trans+VALU floor
// (14 cyc per 64-lane z-group) + ~10us staging/prep + ~35-40us launch/
// ramp overhead == ~118us. Roofline declaration follows on reproduction.

// One layer of the OR-gate net:
//   aw = leaky_clamp(W, 0, 1, 0.1); z = h*aw
//   out[b,o] = sum_i z * softmax_i(tau*z); hout = 1 - out
// Folding: arg = c2*z, c2 = tau*log2(e); sum z*e = (sum arg*e)/c2.
// cw folding: c2*aw = w*(0.1*c2) + med3(w,0,1)*(0.9*c2).
template <int IN, int OUT, int BB, bool FIRST>
__launch_bounds__(256, 4)
__global__ void or_layer(const float* __restrict__ hin,
                         const float* __restrict__ W,
                         const float* __restrict__ tau_ptr,
                         float* __restrict__ hout,
                         float tau_floor) {
  constexpr int OBB = 2;                 // outputs per 16-lane group
  constexpr int NIT = IN / 64;           // 16 lanes x float4 per iter
  constexpr int nOT = OUT / 32;          // 4 waves x 8 outputs per block
  constexpr int IN4 = IN / 4;            // row length in float4

  __shared__ float4 lds_h[BB * IN4];

  const int tid  = threadIdx.x;
  const int lane = tid & 63;
  const int wid  = tid >> 6;
  const int il   = lane & 15;            // i-lane within group
  const int og   = lane >> 4;            // o-group 0..3

  const int ot = blockIdx.x % nOT;
  const int bt = blockIdx.x / nOT;
  const int b0 = bt * BB;
  const int o0 = ot * 32 + wid * 8 + og * OBB;

  const float ta  = tau_ptr[0];
  const float tau = tau_floor + (ta >= 0.0f ? ta : 0.05f * ta);
  const float c2  = tau * 1.44269504088896340736f;  // tau * log2(e)
  const float c01 = 0.1f * c2;           // folded leaky slope
  const float c09 = 0.9f * c2;

  const float4* __restrict__ Wv = (const float4*)W;
  const float4* __restrict__ Hv = (const float4*)hin;

  if (FIRST) {
    // hin is x: (128, IN/2); h = concat(x, 1-x).
    constexpr int HALF4 = IN / 8;
    for (int idx = tid; idx < BB * HALF4; idx += 256) {
      const int r = idx / HALF4;
      const int k = idx - r * HALF4;
      const float4 v = Hv[(b0 + r) * HALF4 + k];
      lds_h[r * IN4 + k] = v;
      lds_h[r * IN4 + HALF4 + k] =
          make_float4(1.0f - v.x, 1.0f - v.y, 1.0f - v.z, 1.0f - v.w);
    }
  } else {
    for (int idx = tid; idx < BB * IN4; idx += 256) {
      const int r = idx / IN4;
      const int k = idx - r * IN4;
      lds_h[r * IN4 + k] = Hv[(b0 + r) * IN4 + k];
    }
  }
  __syncthreads();

  float s[BB][OBB], t[BB][OBB];
#pragma unroll
  for (int r = 0; r < BB; ++r)
#pragma unroll
    for (int c = 0; c < OBB; ++c) { s[r][c] = 0.0f; t[r][c] = 0.0f; }

  // W stream: software pipeline, prefetch distance = 1 ic iteration.
  const float4* wp0 = Wv + (size_t)(o0 + 0) * IN4 + il;
  const float4* wp1 = Wv + (size_t)(o0 + 1) * IN4 + il;
  float4 wcur0 = wp0[0];
  float4 wcur1 = wp1[0];

#pragma unroll 2
  for (int ic = 0; ic < NIT; ++ic) {
    const int icn = (ic + 1 < NIT) ? (ic + 1) : (NIT - 1);
    const float4 wnxt0 = wp0[icn * 16];
    const float4 wnxt1 = wp1[icn * 16];

    float hc[BB][4];
#pragma unroll
    for (int r = 0; r < BB; ++r) {
      const float4 v = lds_h[r * IN4 + ic * 16 + il];
      hc[r][0] = v.x; hc[r][1] = v.y; hc[r][2] = v.z; hc[r][3] = v.w;
    }

    // cw = c2 * leaky_clamp(w): med3 clamp + folded-constant fma,
    // built once per ic, reused across BB rows.
    float cw[OBB][4];
    {
      const float wj0[4] = {wcur0.x, wcur0.y, wcur0.z, wcur0.w};
      const float wj1[4] = {wcur1.x, wcur1.y, wcur1.z, wcur1.w};
#pragma unroll
      for (int j = 0; j < 4; ++j) {
        float m  = fminf(fmaxf(wj0[j], 0.0f), 1.0f);      // v_med3
        cw[0][j] = fmaf(wj0[j], c01, m * c09);
        m        = fminf(fmaxf(wj1[j], 0.0f), 1.0f);
        cw[1][j] = fmaf(wj1[j], c01, m * c09);
      }
    }

    // All-trans inner loop: per z = 1 mul + v_exp (trans) + 1 add + 1 fma.
    // R9 A/B pinned v_exp_f32 at ~8 cyc/wave64, serialized with VALU on
    // the SIMD issue port.
#pragma unroll
    for (int r = 0; r < BB; ++r)
#pragma unroll
      for (int c = 0; c < OBB; ++c)
#pragma unroll
        for (int j = 0; j < 4; ++j) {
          const float arg = cw[c][j] * hc[r][j];
          const float e = EXP2F(arg);
          s[r][c] += e;
          t[r][c]  = fmaf(arg, e, t[r][c]);
        }

    wcur0 = wnxt0;
    wcur1 = wnxt1;
  }

  // Reduce partials across the 16 i-lanes of each group.
#pragma unroll
  for (int m = 1; m < 16; m <<= 1)
#pragma unroll
    for (int r = 0; r < BB; ++r)
#pragma unroll
      for (int c = 0; c < OBB; ++c) {
        s[r][c] += __shfl_xor(s[r][c], m, 64);
        t[r][c] += __shfl_xor(t[r][c], m, 64);
      }

  if (il == 0) {
    const float inv_c2 = 1.0f / c2;
#pragma unroll
    for (int r = 0; r < BB; ++r)
#pragma unroll
      for (int c = 0; c < OBB; ++c) {
        const float out = t[r][c] / s[r][c] * inv_c2;  // sum(z e)/sum(e)
        hout[(b0 + r) * OUT + (o0 + c)] = 1.0f - out;
      }
  }
}

extern "C" void kernel_launch(void* const* d_in, const int* in_sizes, int n_in,
                              void* d_out, int out_size, void* d_ws, size_t ws_size,
                              hipStream_t stream) {
  // setup_inputs() dict order: x, W0, tau0, W1, tau1, W2, tau2, W3, tau3
  const float* x    = (const float*)d_in[0];
  const float* W0   = (const float*)d_in[1];
  const float* tau0 = (const float*)d_in[2];
  const float* W1   = (const float*)d_in[3];
  const float* tau1 = (const float*)d_in[4];
  const float* W2   = (const float*)d_in[5];
  const float* tau2 = (const float*)d_in[6];
  const float* W3   = (const float*)d_in[7];
  const float* tau3 = (const float*)d_in[8];

  float* h1  = (float*)d_ws;        // 128*1024 floats
  float* h2  = h1 + 128 * 1024;     // 128*512
  float* h3  = h2 + 128 * 512;      // 128*256
  float* out = (float*)d_out;       // 128*128

  const double LOGR = 2.9444389791664403;  // log(0.95) - log(0.05) = log(19)
  const float tf1024 = (float)(log(1023.0) + LOGR);
  const float tf512  = (float)(log(511.0)  + LOGR);
  const float tf256  = (float)(log(255.0)  + LOGR);

  // Grid = (OUT/32) * (128/BB) — the validated R9 configuration (118.1 us).
  or_layer<1024, 1024, 4, true ><<<1024, 256, 0, stream>>>(x,  W0, tau0, h1,  tf1024);
  or_layer<1024,  512, 2, false><<<1024, 256, 0, stream>>>(h1, W1, tau1, h2,  tf1024);
  or_layer< 512,  256, 1, false><<<1024, 256, 0, stream>>>(h2, W2, tau2, h3,  tf512);
  or_layer< 256,  128, 1, false><<< 512, 256, 0, stream>>>(h3, W3, tau3, out, tf256);
}